// Round 1
// baseline (741.253 us; speedup 1.0000x reference)
//
#include <hip/hip_runtime.h>

#define NBATCH 32
#define QH 32
#define KVH 8
#define G 4
#define DH 128
#define BS 128
#define NB 512
#define CONST_VAL 10.0f
#define EPS_T 1.1754943508222875e-38f
#define SCALE_F 0.08838834764831845f

// ws layout (floats):
//   partial: NB*KVH*G*DH  = 2,097,152
//   bsum:    NB*KVH*G     = 16,384
//   S:       NBATCH*KVH*G = 1,024
// total ~8.46 MB

__global__ void pa_zero_S(float* S) {
    int i = blockIdx.x * 256 + threadIdx.x;
    if (i < NBATCH * KVH * G) S[i] = 0.f;
}

__global__ __launch_bounds__(256) void pa_pass1(
    const float* __restrict__ query,       // [B, QH, DH]
    const float* __restrict__ key_cache,   // [NCB, BS, KVH, DH]
    const float* __restrict__ value_cache, // [NCB, BS, KVH, DH]
    const float* __restrict__ mapping,     // [NB, B]
    const float* __restrict__ bias,        // [NB, BS]
    const int*   __restrict__ block_list,  // [NB]
    float* __restrict__ partial,           // [NB, KVH, G, DH]
    float* __restrict__ bsum,              // [NB, KVH, G]
    float* __restrict__ S)                 // [B, KVH, G]
{
    const int n  = blockIdx.x;   // 0..NB-1
    const int kh = blockIdx.y;   // 0..KVH-1
    const int t  = threadIdx.x;  // 0..255

    __shared__ float sQ[G][DH];      // 2 KB
    __shared__ float sKV[64][129];   // 33 KB (padded: conflict-free)
    __shared__ float sE[G][BS];      // 2 KB
    __shared__ float sBs[G];

    // ---- build q_n = sum_b map[n,b] * SCALE * query[b, kh*G+g, :] ----
    {
        int i0 = t, i1 = t + 256;                 // 512 slots = 4g x 128d
        int g0 = i0 >> 7, d0 = i0 & 127;
        int g1 = i1 >> 7, d1 = i1 & 127;
        float qa = 0.f, qb = 0.f;
        for (int b = 0; b < NBATCH; ++b) {
            float w = mapping[n * NBATCH + b];
            if (w != 0.f) {
                const float* qrow = query + ((size_t)b * QH + (size_t)kh * G) * DH;
                qa += w * qrow[g0 * DH + d0];
                qb += w * qrow[g1 * DH + d1];
            }
        }
        sQ[g0][d0] = qa * SCALE_F;
        sQ[g1][d1] = qb * SCALE_F;
    }

    const int p = block_list[n];
    const float* kbase = key_cache   + (size_t)p * BS * KVH * DH + (size_t)kh * DH;
    const float* vbase = value_cache + (size_t)p * BS * KVH * DH + (size_t)kh * DH;
    const int row_stride = KVH * DH; // 1024 floats between s rows

    // ---- scores: two 64-row K half-tiles ----
    const int s_l = t & 63;       // lane within wave
    const int g_s = t >> 6;       // wave index = g head
    for (int ph = 0; ph < 2; ++ph) {
        __syncthreads();  // sQ ready (ph0) / prev compute done (ph1)
        // stage 64 rows x 128 floats, coalesced float4
        for (int i = 0; i < 8; ++i) {
            int j = i * 256 + t;      // float4 index in tile
            int row = j >> 5;         // 0..63
            int c4  = j & 31;         // 0..31
            float4 kv = *(const float4*)(kbase + (size_t)(ph * 64 + row) * row_stride + c4 * 4);
            float* dst = &sKV[row][c4 * 4];
            dst[0] = kv.x; dst[1] = kv.y; dst[2] = kv.z; dst[3] = kv.w;
        }
        __syncthreads();
        float acc = 0.f;
        #pragma unroll 8
        for (int d = 0; d < DH; ++d) acc += sKV[s_l][d] * sQ[g_s][d];
        int s = ph * 64 + s_l;
        sE[g_s][s] = __expf(acc + bias[(size_t)n * BS + s] - CONST_VAL);
    }
    __syncthreads();

    // ---- per-block sums: wave w reduces sE[w][:] ----
    {
        int wave = t >> 6, lane = t & 63;
        float v = sE[wave][lane] + sE[wave][lane + 64];
        for (int off = 32; off > 0; off >>= 1) v += __shfl_down(v, off);
        if (lane == 0) sBs[wave] = v;
    }
    __syncthreads();
    if (t < G) {
        float bsv = sBs[t];
        bsum[((size_t)n * KVH + kh) * G + t] = bsv;
        for (int b = 0; b < NBATCH; ++b) {
            float w = mapping[n * NBATCH + b];
            if (w != 0.f) atomicAdd(&S[(b * KVH + kh) * G + t], w * bsv);
        }
    }

    // ---- partial out: two 64-row V half-tiles ----
    const int d_v = t & 127;
    const int gg  = t >> 7;            // 0..1 -> g pair
    float o0 = 0.f, o1 = 0.f;
    for (int ph = 0; ph < 2; ++ph) {
        __syncthreads();  // safe to overwrite sKV
        for (int i = 0; i < 8; ++i) {
            int j = i * 256 + t;
            int row = j >> 5;
            int c4  = j & 31;
            float4 vv = *(const float4*)(vbase + (size_t)(ph * 64 + row) * row_stride + c4 * 4);
            float* dst = &sKV[row][c4 * 4];
            dst[0] = vv.x; dst[1] = vv.y; dst[2] = vv.z; dst[3] = vv.w;
        }
        __syncthreads();
        int g0 = gg * 2, g1 = gg * 2 + 1;
        #pragma unroll 8
        for (int sl = 0; sl < 64; ++sl) {
            float v = sKV[sl][d_v];
            int s = ph * 64 + sl;
            o0 += sE[g0][s] * v;
            o1 += sE[g1][s] * v;
        }
    }
    size_t pb = (((size_t)n * KVH + kh) * G) * DH;
    partial[pb + (size_t)(gg * 2)     * DH + d_v] = o0;
    partial[pb + (size_t)(gg * 2 + 1) * DH + d_v] = o1;
}

__global__ __launch_bounds__(128) void pa_pass2(
    const float* __restrict__ mapping,  // [NB, B]
    const float* __restrict__ partial,  // [NB, KVH, G, DH]
    const float* __restrict__ bsum,     // [NB, KVH, G]
    const float* __restrict__ S,        // [B, KVH, G]
    float* __restrict__ out)            // [B, QH, DH]
{
    int b  = blockIdx.x;   // 0..31
    int kh = blockIdx.y;   // 0..7
    int g  = blockIdx.z;   // 0..3
    int d  = threadIdx.x;  // 0..127
    float acc = 0.f;
    for (int n = 0; n < NB; ++n) {
        float w = mapping[n * NBATCH + b];
        if (w == 0.f) continue;
        float gs = 0.f;
        for (int bb = 0; bb < NBATCH; ++bb) {
            float w2 = mapping[n * NBATCH + bb];
            if (w2 != 0.f) gs += w2 * S[(bb * KVH + kh) * G + g];
        }
        gs += EPS_T;
        float bs = bsum[((size_t)n * KVH + kh) * G + g];
        float den = fmaxf(bs, gs);
        acc += w * partial[(((size_t)n * KVH + kh) * G + g) * DH + d] / den;
    }
    out[((size_t)b * QH + (size_t)kh * G + g) * DH + d] = acc;
}

extern "C" void kernel_launch(void* const* d_in, const int* in_sizes, int n_in,
                              void* d_out, int out_size, void* d_ws, size_t ws_size,
                              hipStream_t stream) {
    const float* query       = (const float*)d_in[0];
    const float* key_cache   = (const float*)d_in[1];
    const float* value_cache = (const float*)d_in[2];
    const float* mapping     = (const float*)d_in[3];
    const float* bias        = (const float*)d_in[4];
    const int*   block_list  = (const int*)d_in[5];
    float* out = (float*)d_out;

    float* partial = (float*)d_ws;
    float* bsum    = partial + (size_t)NB * KVH * G * DH;
    float* S       = bsum + (size_t)NB * KVH * G;

    pa_zero_S<<<4, 256, 0, stream>>>(S);
    pa_pass1<<<dim3(NB, KVH), 256, 0, stream>>>(
        query, key_cache, value_cache, mapping, bias, block_list, partial, bsum, S);
    pa_pass2<<<dim3(NBATCH, KVH, G), 128, 0, stream>>>(mapping, partial, bsum, S, out);
}

// Round 2
// 642.111 us; speedup vs baseline: 1.1544x; 1.1544x over previous
//
#include <hip/hip_runtime.h>

#define NBATCH 32
#define QH 32
#define KVH 8
#define G 4
#define DH 128
#define BS 128
#define NB 512
#define CONST_VAL 10.0f
#define EPS_T 1.1754943508222875e-38f
#define SCALE_F 0.08838834764831845f

// ws layout (floats):
//   partial: NB*KVH*G*DH  = 2,097,152
//   bsum:    NB*KVH*G     = 16,384
//   S:       NBATCH*KVH*G = 1,024
//   den:     NB*KVH*G     = 16,384

__global__ void pa_zero_S(float* S) {
    int i = blockIdx.x * 256 + threadIdx.x;
    if (i < NBATCH * KVH * G) S[i] = 0.f;
}

__global__ __launch_bounds__(256) void pa_pass1(
    const float* __restrict__ query,       // [B, QH, DH]
    const float* __restrict__ key_cache,   // [NCB, BS, KVH, DH]
    const float* __restrict__ value_cache, // [NCB, BS, KVH, DH]
    const float* __restrict__ mapping,     // [NB, B]
    const float* __restrict__ bias,        // [NB, BS]
    const int*   __restrict__ block_list,  // [NB]
    float* __restrict__ partial,           // [NB, KVH, G, DH]
    float* __restrict__ bsum,              // [NB, KVH, G]
    float* __restrict__ S)                 // [B, KVH, G]
{
    const int n  = blockIdx.x;   // 0..NB-1
    const int kh = blockIdx.y;   // 0..KVH-1
    const int t  = threadIdx.x;  // 0..255

    __shared__ float sW[NBATCH];     // mapping row for this n
    __shared__ float sQ[G][DH];      // 2 KB
    __shared__ float sKV[64][129];   // 33 KB (padded: conflict-free)
    __shared__ float sE[G][BS];      // 2 KB
    __shared__ float sBs[G];

    // stage mapping weights once (coalesced), then scan from LDS
    if (t < NBATCH) sW[t] = mapping[n * NBATCH + t];
    __syncthreads();

    // ---- build q_n = sum_b w[b] * SCALE * query[b, kh*G+g, :] ----
    {
        int i0 = t, i1 = t + 256;                 // 512 slots = 4g x 128d
        int g0 = i0 >> 7, d0 = i0 & 127;
        int g1 = i1 >> 7, d1 = i1 & 127;
        float qa = 0.f, qb = 0.f;
        for (int b = 0; b < NBATCH; ++b) {
            float w = sW[b];                      // LDS broadcast, ~free
            if (w != 0.f) {
                const float* qrow = query + ((size_t)b * QH + (size_t)kh * G) * DH;
                qa += w * qrow[g0 * DH + d0];
                qb += w * qrow[g1 * DH + d1];
            }
        }
        sQ[g0][d0] = qa * SCALE_F;
        sQ[g1][d1] = qb * SCALE_F;
    }

    const int p = block_list[n];
    const float* kbase = key_cache   + (size_t)p * BS * KVH * DH + (size_t)kh * DH;
    const float* vbase = value_cache + (size_t)p * BS * KVH * DH + (size_t)kh * DH;
    const int row_stride = KVH * DH; // 1024 floats between s rows

    // ---- scores: two 64-row K half-tiles ----
    const int s_l = t & 63;       // lane within wave
    const int g_s = t >> 6;       // wave index = g head
    for (int ph = 0; ph < 2; ++ph) {
        __syncthreads();  // sQ ready (ph0) / prev compute done (ph1)
        for (int i = 0; i < 8; ++i) {
            int j = i * 256 + t;      // float4 index in tile
            int row = j >> 5;         // 0..63
            int c4  = j & 31;         // 0..31
            float4 kv = *(const float4*)(kbase + (size_t)(ph * 64 + row) * row_stride + c4 * 4);
            float* dst = &sKV[row][c4 * 4];
            dst[0] = kv.x; dst[1] = kv.y; dst[2] = kv.z; dst[3] = kv.w;
        }
        __syncthreads();
        float acc = 0.f;
        #pragma unroll 8
        for (int d = 0; d < DH; ++d) acc += sKV[s_l][d] * sQ[g_s][d];
        int s = ph * 64 + s_l;
        sE[g_s][s] = __expf(acc + bias[(size_t)n * BS + s] - CONST_VAL);
    }
    __syncthreads();

    // ---- per-block sums: wave w reduces sE[w][:] ----
    {
        int wave = t >> 6, lane = t & 63;
        float v = sE[wave][lane] + sE[wave][lane + 64];
        for (int off = 32; off > 0; off >>= 1) v += __shfl_down(v, off);
        if (lane == 0) sBs[wave] = v;
    }
    __syncthreads();
    if (t < G) {
        float bsv = sBs[t];
        bsum[((size_t)n * KVH + kh) * G + t] = bsv;
        for (int b = 0; b < NBATCH; ++b) {
            float w = sW[b];
            if (w != 0.f) atomicAdd(&S[(b * KVH + kh) * G + t], w * bsv);
        }
    }

    // ---- partial out: two 64-row V half-tiles ----
    const int d_v = t & 127;
    const int gg  = t >> 7;            // 0..1 -> g pair
    float o0 = 0.f, o1 = 0.f;
    for (int ph = 0; ph < 2; ++ph) {
        __syncthreads();  // safe to overwrite sKV
        for (int i = 0; i < 8; ++i) {
            int j = i * 256 + t;
            int row = j >> 5;
            int c4  = j & 31;
            float4 vv = *(const float4*)(vbase + (size_t)(ph * 64 + row) * row_stride + c4 * 4);
            float* dst = &sKV[row][c4 * 4];
            dst[0] = vv.x; dst[1] = vv.y; dst[2] = vv.z; dst[3] = vv.w;
        }
        __syncthreads();
        int g0 = gg * 2, g1 = gg * 2 + 1;
        #pragma unroll 8
        for (int sl = 0; sl < 64; ++sl) {
            float v = sKV[sl][d_v];
            int s = ph * 64 + sl;
            o0 += sE[g0][s] * v;
            o1 += sE[g1][s] * v;
        }
    }
    size_t pb = (((size_t)n * KVH + kh) * G) * DH;
    partial[pb + (size_t)(gg * 2)     * DH + d_v] = o0;
    partial[pb + (size_t)(gg * 2 + 1) * DH + d_v] = o1;
}

// den[n,kh,g] = max(bsum[n,kh,g], sum_b map[n,b]*S[b,kh,g] + EPS)
__global__ __launch_bounds__(256) void pa_den(
    const float* __restrict__ mapping,  // [NB, B]
    const float* __restrict__ bsum,     // [NB, KVH, G]
    const float* __restrict__ S,        // [B, KVH, G]
    float* __restrict__ den)            // [NB, KVH, G]
{
    int i = blockIdx.x * 256 + threadIdx.x;
    if (i >= NB * KVH * G) return;
    int g  = i & (G - 1);
    int kh = (i / G) & (KVH - 1);
    int n  = i / (G * KVH);
    float gs = 0.f;
    for (int b = 0; b < NBATCH; ++b)
        gs += mapping[n * NBATCH + b] * S[(b * KVH + kh) * G + g];
    gs += EPS_T;
    den[i] = fmaxf(bsum[i], gs);
}

__global__ __launch_bounds__(256) void pa_pass2(
    const float* __restrict__ mapping,  // [NB, B]
    const float* __restrict__ partial,  // [NB, KVH, G, DH]
    const float* __restrict__ den,      // [NB, KVH, G]
    float* __restrict__ out)            // [B, QH, DH]
{
    int b  = blockIdx.x;   // 0..31
    int kh = blockIdx.y;   // 0..7
    int t  = threadIdx.x;  // 0..255
    int g  = t >> 7;       // 0..1  (also handles g+2)
    int d  = t & 127;

    __shared__ float sWc[NB];  // mapping column b
    for (int i = t; i < NB; i += 256) sWc[i] = mapping[i * NBATCH + b];
    __syncthreads();

    float a0 = 0.f, a1 = 0.f;
    for (int n = 0; n < NB; ++n) {
        float w = sWc[n];
        if (w == 0.f) continue;
        int di = (n * KVH + kh) * G;
        size_t pb = (size_t)di * DH;
        a0 += w * partial[pb + (size_t)g * DH + d] / den[di + g];
        a1 += w * partial[pb + (size_t)(g + 2) * DH + d] / den[di + g + 2];
    }
    size_t ob = ((size_t)b * QH + (size_t)kh * G) * DH;
    out[ob + (size_t)g * DH + d]       = a0;
    out[ob + (size_t)(g + 2) * DH + d] = a1;
}

extern "C" void kernel_launch(void* const* d_in, const int* in_sizes, int n_in,
                              void* d_out, int out_size, void* d_ws, size_t ws_size,
                              hipStream_t stream) {
    const float* query       = (const float*)d_in[0];
    const float* key_cache   = (const float*)d_in[1];
    const float* value_cache = (const float*)d_in[2];
    const float* mapping     = (const float*)d_in[3];
    const float* bias        = (const float*)d_in[4];
    const int*   block_list  = (const int*)d_in[5];
    float* out = (float*)d_out;

    float* partial = (float*)d_ws;
    float* bsum    = partial + (size_t)NB * KVH * G * DH;
    float* S       = bsum + (size_t)NB * KVH * G;
    float* den     = S + (size_t)NBATCH * KVH * G;

    pa_zero_S<<<4, 256, 0, stream>>>(S);
    pa_pass1<<<dim3(NB, KVH), 256, 0, stream>>>(
        query, key_cache, value_cache, mapping, bias, block_list, partial, bsum, S);
    pa_den<<<(NB * KVH * G + 255) / 256, 256, 0, stream>>>(mapping, bsum, S, den);
    pa_pass2<<<dim3(NBATCH, KVH), 256, 0, stream>>>(mapping, partial, den, out);
}